// Round 2
// baseline (537.044 us; speedup 1.0000x reference)
//
#include <hip/hip_runtime.h>

#define TZ 128      // TOKEN_Z
#define R_MAX 32
#define S_MAX 2
#define NROW 139    // W rows: W_pos[0,66) W_tok[66,132) w_ent=132 W_ch[133,139)

typedef float v4f __attribute__((ext_vector_type(4)));

// One block owns TWO full output rows (i0, i0+1) = a contiguous 1-MiB span.
// Inner loop stores one dense 4-KB chunk per iteration, walking linearly --
// identical stream shape to the 6.3 TB/s fillBuffer.
__global__ __launch_bounds__(256, 2) void relpos_kernel(
    const int* __restrict__ asym, const int* __restrict__ resi,
    const int* __restrict__ ent,  const int* __restrict__ tok,
    const int* __restrict__ sym,  const int* __restrict__ cyc,
    const float* __restrict__ W,  float* __restrict__ out, int L)
{
    __shared__ v4f sW[NROW * 32];            // 71,168 B -- full W table
    __shared__ unsigned int sidx[2 * 1024];  // 8 KB packed indices, [ii][jr][t]

    const int tid = threadIdx.x;
    const int i0  = blockIdx.x * 2;

    const v4f* __restrict__ Wv = (const v4f*)W;

    // ---- stage W into LDS (once per block; L2/LLC-resident source) ----
    for (int idx = tid; idx < NROW * 32; idx += 256)
        sW[idx] = Wv[idx];

    // ---- i-side scalars (block-uniform) ----
    int ai_[2], ri_[2], ei_[2], ti_[2], si_[2];
    #pragma unroll
    for (int ii = 0; ii < 2; ++ii) {
        ai_[ii] = asym[i0 + ii]; ri_[ii] = resi[i0 + ii]; ei_[ii] = ent[i0 + ii];
        ti_[ii] = tok[i0 + ii];  si_[ii] = sym[i0 + ii];
    }

    // ---- phase 1: packed indices for 2 rows x 1024 j ----
    #pragma unroll
    for (int q = 0; q < 4; ++q) {
        const int j  = q * 256 + tid;
        const int aj = asym[j], rj = resi[j], ej = ent[j];
        const int tj = tok[j],  sj = sym[j],  cj = cyc[j];
        const int period = (cj > 0) ? cj : 10000;
        const float inv_p = 1.0f / (float)period;
        // transposed slot so phase 2 reads 4 consecutive t's per jr-group
        const int tr = (j & 7) * 128 + (j >> 3);

        #pragma unroll
        for (int ii = 0; ii < 2; ++ii) {
            const bool same_chain = (ai_[ii] == aj);
            const bool same_res   = (ri_[ii] == rj);
            const bool same_ent   = (ei_[ii] == ej);

            int rel = ri_[ii] - rj;
            // jnp.round = round-half-even = rintf; astype(int32) truncates
            const float qq = rintf((float)rel * inv_p);
            rel -= (int)((float)period * qq);

            int dr = rel + R_MAX;
            dr = dr < 0 ? 0 : (dr > 2 * R_MAX ? 2 * R_MAX : dr);
            if (!same_chain) dr = 2 * R_MAX + 1;

            int dt = ti_[ii] - tj + R_MAX;
            dt = dt < 0 ? 0 : (dt > 2 * R_MAX ? 2 * R_MAX : dt);
            if (!(same_chain && same_res)) dt = 2 * R_MAX + 1;

            int dc = si_[ii] - sj + S_MAX;
            dc = dc < 0 ? 0 : (dc > 2 * S_MAX ? 2 * S_MAX : dc);
            if (same_chain) dc = 2 * S_MAX + 1;

            sidx[ii * 1024 + tr] = (unsigned)dr | ((unsigned)dt << 8)
                                 | ((unsigned)dc << 16)
                                 | ((unsigned)(same_ent ? 1u : 0u) << 24);
        }
    }

    const int zq = tid & 31;   // float4 chunk of z
    const int jr = tid >> 5;   // 0..7
    const v4f we = Wv[132 * 32 + zq];

    __syncthreads();

    // ---- phase 2: LDS gathers + perfectly linear streaming stores ----
    // v4f linear index of (ii, j, zq): ii*32768 + j*32 + zq, j = t*8 + jr
    v4f* __restrict__ outv = (v4f*)out + (size_t)blockIdx.x * (2 * 1024 * 32);

    #pragma unroll
    for (int ii = 0; ii < 2; ++ii) {
        const unsigned* __restrict__ sip = &sidx[ii * 1024 + jr * 128];
        v4f* __restrict__ op = outv + ii * 32768 + zq;

        #pragma unroll 2
        for (int t4 = 0; t4 < 32; ++t4) {
            // 4 packed indices in one broadcast ds_read_b128 (same addr
            // across the 32 lanes of a jr-group -> conflict-free)
            const uint4 pk4 = *(const uint4*)&sip[t4 * 4];

            #pragma unroll
            for (int k = 0; k < 4; ++k) {
                const unsigned pk = (&pk4.x)[k];
                const int dr = pk & 0xFF;
                const int dt = (pk >> 8) & 0xFF;
                const int dc = (pk >> 16) & 0xFF;
                const float se = (pk >> 24) ? 1.0f : 0.0f;

                const v4f a = sW[dr * 32 + zq];
                const v4f b = sW[(66 + dt) * 32 + zq];
                const v4f c = sW[(133 + dc) * 32 + zq];

                const int t = t4 * 4 + k;          // j = t*8 + jr
                // block stores a dense 4-KB chunk per t; linear in t
                op[(t * 8 + jr) * 32] = a + b + c + se * we;
            }
        }
    }
}

extern "C" void kernel_launch(void* const* d_in, const int* in_sizes, int n_in,
                              void* d_out, int out_size, void* d_ws, size_t ws_size,
                              hipStream_t stream) {
    const int* asym = (const int*)d_in[0];
    const int* resi = (const int*)d_in[1];
    const int* ent  = (const int*)d_in[2];
    const int* tok  = (const int*)d_in[3];
    const int* sym  = (const int*)d_in[4];
    const int* cyc  = (const int*)d_in[5];
    const float* W  = (const float*)d_in[6];
    float* out      = (float*)d_out;

    const int L = in_sizes[0];          // B=1, L=1024
    dim3 grid(L / 2);                   // 512 blocks, one 1-MiB span each
    dim3 block(256);
    relpos_kernel<<<grid, block, 0, stream>>>(asym, resi, ent, tok, sym, cyc, W, out, L);
}